// Round 6
// baseline (2920.237 us; speedup 1.0000x reference)
//
#include <hip/hip_runtime.h>
#include <hip/hip_bf16.h>
#include <math.h>

// Problem constants
#define BATCH   256
#define T_STEPS 4096
#define IN_DIM  28
#define HID     128
#define GATES   512   // 4*HID
#define OUT_DIM 10

#define HPAD    16                    // ushort pad: buf/par regions hit different banks
#define PARSTRIDE (HID + HPAD)        // ushorts between par=0 and par=1 regions
#define BUFSTRIDE (2 * PARSTRIDE)     // ushorts between buf 0 and buf 1

typedef short bf16x8 __attribute__((ext_vector_type(8)));  // 8 bf16 in 4 VGPRs
typedef float f32x4  __attribute__((ext_vector_type(4)));

__device__ __forceinline__ float frcp_fast(float x) {
    return __builtin_amdgcn_rcpf(x);
}

__device__ __forceinline__ float sigm(float x) {
    // 1/(1+2^(-x*log2e)) — mul(+exp2) / add / rcp
    float e = __builtin_exp2f(x * -1.44269504f);
    return frcp_fast(1.0f + e);
}

__device__ __forceinline__ float tanh_fast(float x) {
    // tanh(x) = sign(x)*(1-e)/(1+e), e = 2^(-2|x|*log2e); abs folds into the mul
    float e = __builtin_exp2f(fabsf(x) * -2.88539008f);
    float r = (1.0f - e) * frcp_fast(1.0f + e);
    return copysignf(r, x);
}

__device__ __forceinline__ unsigned short f2bf(float f) {
    __hip_bfloat16 h = __float2bfloat16(f);   // RNE
    return __builtin_bit_cast(unsigned short, h);
}
__device__ __forceinline__ float bf2f(unsigned short u) {
    return __bfloat162float(__builtin_bit_cast(__hip_bfloat16, u));
}

// ---------------------------------------------------------------------------
// Kernel 1: input projection for batch element 255, UNIT-MAJOR output:
// gx2[t, u, gt] = dot(x255[t,:], w_ih[gt*128+u,:]) + b_ih[..] + b_hh[..]
// ---------------------------------------------------------------------------
__global__ __launch_bounds__(GATES) void k_inproj(const float* __restrict__ x255,
                                                  const float* __restrict__ w_ih,
                                                  const float* __restrict__ b_ih,
                                                  const float* __restrict__ b_hh,
                                                  float* __restrict__ gx2) {
    const int t = blockIdx.x;
    const int g = threadIdx.x;          // gate row 0..511 (i|f|g|o blocks of 128)
    const int unit = g & (HID - 1);
    const int quad = g >> 7;
    __shared__ float xs[IN_DIM];
    if (g < IN_DIM) xs[g] = x255[t * IN_DIM + g];
    __syncthreads();
    float acc = b_ih[g] + b_hh[g];
    const float* __restrict__ wr = w_ih + g * IN_DIM;
#pragma unroll
    for (int k = 0; k < IN_DIM; ++k) acc += wr[k] * xs[k];
    gx2[t * GATES + unit * 4 + quad] = acc;
}

// ---------------------------------------------------------------------------
// Kernel 2 (main): MFMA LSTM scan — 512 threads (8 waves), unit-major.
// R5 structure (verified) + VALU squeeze:
//  - t-loop unrolled x2: buffer indices are literals -> ds_read/write use
//    immediate offsets off loop-invariant per-lane bases (no per-step addr math)
//  - gx rides MFMA's C operand: acc[gt] = splat(par ? 0 : gcur[gt]); regs
//    r != r_sel are read by no lane, so the splat is safe. Removes the
//    post-MFMA gx adds from the critical chain.
//  - h buffers padded: [buf][par][HID+16] -> different bank groups (R5 had
//    524288 conflict-cycles/dispatch from 512B-aligned h_hi/h_lo).
// Lane decode (R4 bugfix, unchanged): pair lanes (l, l^1) share a unit
// (r_sel=(cidx>>1)&3); shfl_xor(v,1) sums hi+lo partials of the SAME unit.
// ---------------------------------------------------------------------------
__global__ __attribute__((amdgpu_flat_work_group_size(512, 512),
                          amdgpu_waves_per_eu(2, 2)))
void k_scan_mfma(const float* __restrict__ gx2,
                 const float* __restrict__ w_hh,
                 float* __restrict__ hs) {
    const int tid   = threadIdx.x;
    const int w     = tid >> 6;         // wave 0..7
    const int l     = tid & 63;         // lane 0..63
    const int q     = l >> 4;           // k-group / row-group 0..3
    const int cidx  = l & 15;           // D column this lane reads
    const int par   = cidx & 1;         // 0: hi-partial path, 1: lo
    const int r_sel = (cidx >> 1) & 3;  // acc reg = unit within q-group (pair-invariant)
    const int ubase = w * 16;
    const int u     = ubase + q * 4 + r_sel;   // unit this lane finalizes
    const bool writer = (par == 0) && (cidx < 8);  // cidx in {0,2,4,6}
    const float pz = par ? 0.0f : 1.0f; // gx goes only into the hi-parity leg

    __shared__ __align__(16) unsigned short hb[2 * BUFSTRIDE];

    // ---- one-time: A-frags wf[gate_type][kt] (64 VGPRs) ----
    bf16x8 wf[4][4];
#pragma unroll
    for (int gt = 0; gt < 4; ++gt) {
        const int row = gt * HID + ubase + cidx;
        const float* __restrict__ wr = w_hh + row * HID;
#pragma unroll
        for (int kt = 0; kt < 4; ++kt) {
            const int k0 = kt * 32 + q * 8;
            bf16x8 v;
#pragma unroll
            for (int j = 0; j < 8; ++j) v[j] = (short)f2bf(wr[k0 + j]);
            wf[gt][kt] = v;
        }
    }

    // zero both buffers (both parities)
    if (tid < HID) {
        hb[0 * BUFSTRIDE + 0 * PARSTRIDE + tid] = 0;
        hb[0 * BUFSTRIDE + 1 * PARSTRIDE + tid] = 0;
        hb[1 * BUFSTRIDE + 0 * PARSTRIDE + tid] = 0;
        hb[1 * BUFSTRIDE + 1 * PARSTRIDE + tid] = 0;
    }
    float c = 0.0f;
    // loop-invariant per-lane bases
    const unsigned short* __restrict__ hq = &hb[par * PARSTRIDE + q * 8]; // B-frag read base
    unsigned short* __restrict__ wpt = &hb[u];                            // writer base

    float4 gnext = *reinterpret_cast<const float4*>(gx2 + u * 4);  // t=0
    __syncthreads();

    // One unrolled step. RB/WB are literals -> LDS addressing folds to
    // immediate offsets; gx rides the MFMA C operand.
#define LSTM_STEP(T, RB, WB)                                                   \
    {                                                                          \
        float4 gcur = gnext;                                                   \
        if ((T) + 1 < T_STEPS)                                                 \
            gnext = *reinterpret_cast<const float4*>(gx2 + ((T) + 1) * GATES + u * 4); \
        bf16x8 bf0 = *reinterpret_cast<const bf16x8*>(hq + (RB) * BUFSTRIDE + 0 * 32); \
        bf16x8 bf1 = *reinterpret_cast<const bf16x8*>(hq + (RB) * BUFSTRIDE + 1 * 32); \
        bf16x8 bf2 = *reinterpret_cast<const bf16x8*>(hq + (RB) * BUFSTRIDE + 2 * 32); \
        bf16x8 bf3 = *reinterpret_cast<const bf16x8*>(hq + (RB) * BUFSTRIDE + 3 * 32); \
        float g0 = pz * gcur.x, g1 = pz * gcur.y, g2 = pz * gcur.z, g3 = pz * gcur.w; \
        f32x4 a0 = {g0, g0, g0, g0};                                           \
        f32x4 a1 = {g1, g1, g1, g1};                                           \
        f32x4 a2 = {g2, g2, g2, g2};                                           \
        f32x4 a3 = {g3, g3, g3, g3};                                           \
        a0 = __builtin_amdgcn_mfma_f32_16x16x32_bf16(wf[0][0], bf0, a0, 0, 0, 0); \
        a1 = __builtin_amdgcn_mfma_f32_16x16x32_bf16(wf[1][0], bf0, a1, 0, 0, 0); \
        a2 = __builtin_amdgcn_mfma_f32_16x16x32_bf16(wf[2][0], bf0, a2, 0, 0, 0); \
        a3 = __builtin_amdgcn_mfma_f32_16x16x32_bf16(wf[3][0], bf0, a3, 0, 0, 0); \
        a0 = __builtin_amdgcn_mfma_f32_16x16x32_bf16(wf[0][1], bf1, a0, 0, 0, 0); \
        a1 = __builtin_amdgcn_mfma_f32_16x16x32_bf16(wf[1][1], bf1, a1, 0, 0, 0); \
        a2 = __builtin_amdgcn_mfma_f32_16x16x32_bf16(wf[2][1], bf1, a2, 0, 0, 0); \
        a3 = __builtin_amdgcn_mfma_f32_16x16x32_bf16(wf[3][1], bf1, a3, 0, 0, 0); \
        a0 = __builtin_amdgcn_mfma_f32_16x16x32_bf16(wf[0][2], bf2, a0, 0, 0, 0); \
        a1 = __builtin_amdgcn_mfma_f32_16x16x32_bf16(wf[1][2], bf2, a1, 0, 0, 0); \
        a2 = __builtin_amdgcn_mfma_f32_16x16x32_bf16(wf[2][2], bf2, a2, 0, 0, 0); \
        a3 = __builtin_amdgcn_mfma_f32_16x16x32_bf16(wf[3][2], bf2, a3, 0, 0, 0); \
        a0 = __builtin_amdgcn_mfma_f32_16x16x32_bf16(wf[0][3], bf3, a0, 0, 0, 0); \
        a1 = __builtin_amdgcn_mfma_f32_16x16x32_bf16(wf[1][3], bf3, a1, 0, 0, 0); \
        a2 = __builtin_amdgcn_mfma_f32_16x16x32_bf16(wf[2][3], bf3, a2, 0, 0, 0); \
        a3 = __builtin_amdgcn_mfma_f32_16x16x32_bf16(wf[3][3], bf3, a3, 0, 0, 0); \
        float p0 = 0.f, p1 = 0.f, p2 = 0.f, p3 = 0.f;                          \
        _Pragma("unroll")                                                      \
        for (int r = 0; r < 4; ++r) {                                          \
            if (r == r_sel) { p0 = a0[r]; p1 = a1[r]; p2 = a2[r]; p3 = a3[r]; } \
        }                                                                      \
        p0 += __shfl_xor(p0, 1);                                               \
        p1 += __shfl_xor(p1, 1);                                               \
        p2 += __shfl_xor(p2, 1);                                               \
        p3 += __shfl_xor(p3, 1);                                               \
        float iv = sigm(p0);                                                   \
        float fv = sigm(p1);                                                   \
        float gv = tanh_fast(p2);                                              \
        float ov = sigm(p3);                                                   \
        c = fv * c + iv * gv;                                                  \
        float h = ov * tanh_fast(c);                                           \
        if (writer) {                                                          \
            unsigned short hi = f2bf(h);                                       \
            wpt[(WB) * BUFSTRIDE] = hi;                                        \
            wpt[(WB) * BUFSTRIDE + PARSTRIDE] = f2bf(h - bf2f(hi));            \
            hs[(T) * HID + u] = h;                                             \
        }                                                                      \
        __syncthreads();                                                       \
    }

    for (int t = 0; t < T_STEPS; t += 2) {
        LSTM_STEP(t, 1, 0);       // even step: read buf1 (zeroed at t=0), write buf0
        LSTM_STEP(t + 1, 0, 1);   // odd step: read buf0, write buf1
    }
#undef LSTM_STEP
}

// ---------------------------------------------------------------------------
// Fallback scan (fused input projection, f32 VALU) — only if d_ws too small.
// ---------------------------------------------------------------------------
__global__ __launch_bounds__(GATES) void k_scan_valu(const float* __restrict__ w_hh,
                                                     float* __restrict__ hs,
                                                     const float* __restrict__ x255,
                                                     const float* __restrict__ w_ih,
                                                     const float* __restrict__ b_ih,
                                                     const float* __restrict__ b_hh) {
    const int g    = threadIdx.x;
    const int quad = g >> 7;

    __shared__ float h_sh[HID];
    __shared__ float act_sh[GATES];
    __shared__ float xs[IN_DIM];

    float4 wv[HID / 4];
    const float4* __restrict__ wrow = reinterpret_cast<const float4*>(w_hh + g * HID);
#pragma unroll
    for (int k = 0; k < HID / 4; ++k) wv[k] = wrow[k];

    float bsum = b_ih[g] + b_hh[g];
    float wih[IN_DIM];
#pragma unroll
    for (int k = 0; k < IN_DIM; ++k) wih[k] = w_ih[g * IN_DIM + k];

    if (g < HID) h_sh[g] = 0.0f;
    float c = 0.0f;
    __syncthreads();

    for (int t = 0; t < T_STEPS; ++t) {
        __syncthreads();
        if (g < IN_DIM) xs[g] = x255[t * IN_DIM + g];
        __syncthreads();
        float a0 = bsum, a1 = 0.0f, a2 = 0.0f, a3 = 0.0f;
#pragma unroll
        for (int k = 0; k < IN_DIM; ++k) a0 += wih[k] * xs[k];

        const float4* __restrict__ h4 = reinterpret_cast<const float4*>(h_sh);
#pragma unroll
        for (int k = 0; k < HID / 4; ++k) {
            float4 hv = h4[k];
            a0 += wv[k].x * hv.x;
            a1 += wv[k].y * hv.y;
            a2 += wv[k].z * hv.z;
            a3 += wv[k].w * hv.w;
        }
        float pre = (a0 + a1) + (a2 + a3);
        float a = (quad == 2) ? tanh_fast(pre) : sigm(pre);
        act_sh[g] = a;
        __syncthreads();

        if (g < HID) {
            float iv = act_sh[g];
            float fv = act_sh[HID + g];
            float gv = act_sh[2 * HID + g];
            float ov = act_sh[3 * HID + g];
            c = fv * c + iv * gv;
            float h = ov * tanh_fast(c);
            h_sh[g] = h;
            hs[t * HID + g] = h;
        }
        __syncthreads();
    }
}

// ---------------------------------------------------------------------------
// Kernel 3: final FC — out[t, o] = dot(hs[t, :], w_fc[o, :]) + b_fc[o]
// ---------------------------------------------------------------------------
__global__ __launch_bounds__(256) void k_fc(const float* __restrict__ hs,
                                            const float* __restrict__ w_fc,
                                            const float* __restrict__ b_fc,
                                            float* __restrict__ out) {
    const int idx = blockIdx.x * blockDim.x + threadIdx.x;
    if (idx >= T_STEPS * OUT_DIM) return;
    const int t = idx / OUT_DIM;
    const int o = idx - t * OUT_DIM;
    const float* __restrict__ hrow = hs + t * HID;
    const float* __restrict__ wrow = w_fc + o * HID;
    float acc = b_fc[o];
#pragma unroll 8
    for (int k = 0; k < HID; ++k) acc += hrow[k] * wrow[k];
    out[idx] = acc;
}

// ---------------------------------------------------------------------------
extern "C" void kernel_launch(void* const* d_in, const int* in_sizes, int n_in,
                              void* d_out, int out_size, void* d_ws, size_t ws_size,
                              hipStream_t stream) {
    const float* x    = (const float*)d_in[0];  // [B, T, I]
    const float* w_ih = (const float*)d_in[1];  // [4H, I]
    const float* w_hh = (const float*)d_in[2];  // [4H, H]
    const float* b_ih = (const float*)d_in[3];  // [4H]
    const float* b_hh = (const float*)d_in[4];  // [4H]
    const float* w_fc = (const float*)d_in[5];  // [OUT, H]
    const float* b_fc = (const float*)d_in[6];  // [OUT]
    float* out = (float*)d_out;                 // [T, OUT]

    // Only batch element B-1 is observable in the reference output.
    const float* x255 = x + (size_t)(BATCH - 1) * T_STEPS * IN_DIM;

    float* hs = (float*)d_ws;                                  // 4096*128 f32 = 2 MB
    float* gx2 = hs + (size_t)T_STEPS * HID;                   // 4096*512 f32 = 8 MB (unit-major)
    const size_t need_full = (size_t)(T_STEPS * HID + T_STEPS * GATES) * sizeof(float);

    if (ws_size >= need_full) {
        k_inproj<<<T_STEPS, GATES, 0, stream>>>(x255, w_ih, b_ih, b_hh, gx2);
        k_scan_mfma<<<1, GATES, 0, stream>>>(gx2, w_hh, hs);
    } else {
        k_scan_valu<<<1, GATES, 0, stream>>>(w_hh, hs, x255, w_ih, b_ih, b_hh);
    }

    const int n = T_STEPS * OUT_DIM;
    k_fc<<<(n + 255) / 256, 256, 0, stream>>>(hs, w_fc, b_fc, out);
}

// Round 7
// 2390.852 us; speedup vs baseline: 1.2214x; 1.2214x over previous
//
#include <hip/hip_runtime.h>
#include <hip/hip_bf16.h>
#include <math.h>

// Problem constants
#define BATCH   256
#define T_STEPS 4096
#define IN_DIM  28
#define HID     128
#define GATES   512   // 4*HID
#define OUT_DIM 10

#define HPAD    16                    // ushort pad: buf/par regions hit different banks
#define PARSTRIDE (HID + HPAD)        // ushorts between par=0 and par=1 regions
#define BUFSTRIDE (2 * PARSTRIDE)     // ushorts between buf 0 and buf 1

typedef short bf16x8 __attribute__((ext_vector_type(8)));  // 8 bf16 in 4 VGPRs
typedef float f32x4  __attribute__((ext_vector_type(4)));

__device__ __forceinline__ float frcp_fast(float x) {
    return __builtin_amdgcn_rcpf(x);
}

__device__ __forceinline__ float sigm(float x) {
    // 1/(1+2^(-x*log2e)) — mul(+exp2) / add / rcp
    float e = __builtin_exp2f(x * -1.44269504f);
    return frcp_fast(1.0f + e);
}

__device__ __forceinline__ float tanh_fast(float x) {
    // tanh(x) = sign(x)*(1-e)/(1+e), e = 2^(-2|x|*log2e); abs folds into the mul
    float e = __builtin_exp2f(fabsf(x) * -2.88539008f);
    float r = (1.0f - e) * frcp_fast(1.0f + e);
    return copysignf(r, x);
}

__device__ __forceinline__ unsigned short f2bf(float f) {
    __hip_bfloat16 h = __float2bfloat16(f);   // RNE
    return __builtin_bit_cast(unsigned short, h);
}
__device__ __forceinline__ float bf2f(unsigned short u) {
    return __bfloat162float(__builtin_bit_cast(__hip_bfloat16, u));
}

// ---------------------------------------------------------------------------
// Kernel 1: input projection for batch element 255, UNIT-MAJOR output:
// gx2[t, u, gt] = dot(x255[t,:], w_ih[gt*128+u,:]) + b_ih[..] + b_hh[..]
// ---------------------------------------------------------------------------
__global__ __launch_bounds__(GATES) void k_inproj(const float* __restrict__ x255,
                                                  const float* __restrict__ w_ih,
                                                  const float* __restrict__ b_ih,
                                                  const float* __restrict__ b_hh,
                                                  float* __restrict__ gx2) {
    const int t = blockIdx.x;
    const int g = threadIdx.x;          // gate row 0..511 (i|f|g|o blocks of 128)
    const int unit = g & (HID - 1);
    const int quad = g >> 7;
    __shared__ float xs[IN_DIM];
    if (g < IN_DIM) xs[g] = x255[t * IN_DIM + g];
    __syncthreads();
    float acc = b_ih[g] + b_hh[g];
    const float* __restrict__ wr = w_ih + g * IN_DIM;
#pragma unroll
    for (int k = 0; k < IN_DIM; ++k) acc += wr[k] * xs[k];
    gx2[t * GATES + unit * 4 + quad] = acc;
}

// ---------------------------------------------------------------------------
// Kernel 2 (main): MFMA LSTM scan — 512 threads (8 waves), unit-major.
//
// OPERAND-SWAPPED layout (R6 lesson: kill the cross-lane epilogue):
//   D = A*B with A = h (16 rows: EVEN rows h_hi, ODD rows h_lo), B = W_hh
//   (col n = unit ubase+n). Lane l (m89-verified D: col=l&15, row=(l>>4)*4+r)
//   then holds, in col cidx = ITS OWN UNIT:
//     reg0 = row q*4   (even) = gx + hi-contribution   (gx rides C reg0)
//     reg1 = row q*4+1 (odd)  = lo-contribution
//   pre = acc[0] + acc[1] — STATIC regs. No v_cmp/cndmask select, no
//   shfl_xor swizzles, no pz masking. Per-lane frag data/LDS reads are
//   identical to R5/R6 (B-frag = old wf; A-frag = old parity-selected h read).
//   A-row=identity verified by R5 pass; D verified (m89); B-col=identity
//   verified by guide's end-to-end GEMMs (wrong permutation => loud failure).
//
// All 4 q-replicas of a unit compute identical values (even rows all = hi,
// odd all = lo); q==0 lanes write. One barrier per step, double-buffered h,
// padded parity regions (R6: conflicts = 0).
// ---------------------------------------------------------------------------
__global__ __attribute__((amdgpu_flat_work_group_size(512, 512),
                          amdgpu_waves_per_eu(2, 2)))
void k_scan_mfma(const float* __restrict__ gx2,
                 const float* __restrict__ w_hh,
                 float* __restrict__ hs) {
    const int tid   = threadIdx.x;
    const int w     = tid >> 6;         // wave 0..7
    const int l     = tid & 63;         // lane 0..63
    const int q     = l >> 4;           // k-group / D row-group 0..3
    const int cidx  = l & 15;           // D column = unit within wave
    const int par   = cidx & 1;         // A-row parity: 0 -> h_hi, 1 -> h_lo
    const int ubase = w * 16;
    const int u     = ubase + cidx;     // unit this lane finalizes
    const bool writer = (q == 0);       // one q-replica writes

    __shared__ __align__(16) unsigned short hb[2 * BUFSTRIDE];

    // ---- one-time: B-frags wb_[gate_type][kt] (64 VGPRs) ----
    // lane l holds B[k = kt*32 + q*8 + j][col = cidx] = W_hh[gt*128+u][k]
    bf16x8 wb_[4][4];
#pragma unroll
    for (int gt = 0; gt < 4; ++gt) {
        const int row = gt * HID + u;
        const float* __restrict__ wr = w_hh + row * HID;
#pragma unroll
        for (int kt = 0; kt < 4; ++kt) {
            const int k0 = kt * 32 + q * 8;
            bf16x8 v;
#pragma unroll
            for (int j = 0; j < 8; ++j) v[j] = (short)f2bf(wr[k0 + j]);
            wb_[gt][kt] = v;
        }
    }

    // zero both buffers (both parities)
    if (tid < HID) {
        hb[0 * BUFSTRIDE + 0 * PARSTRIDE + tid] = 0;
        hb[0 * BUFSTRIDE + 1 * PARSTRIDE + tid] = 0;
        hb[1 * BUFSTRIDE + 0 * PARSTRIDE + tid] = 0;
        hb[1 * BUFSTRIDE + 1 * PARSTRIDE + tid] = 0;
    }
    float c = 0.0f;                     // cell state (4x replicated per unit)
    // loop-invariant per-lane bases
    const unsigned short* __restrict__ hq = &hb[par * PARSTRIDE + q * 8]; // A-frag read base
    unsigned short* __restrict__ wpt = &hb[u];                            // writer base

    float4 gnext = *reinterpret_cast<const float4*>(gx2 + u * 4);  // t=0
    __syncthreads();

#define LSTM_STEP(T, RB, WB)                                                   \
    {                                                                          \
        float4 gcur = gnext;                                                   \
        if ((T) + 1 < T_STEPS)                                                 \
            gnext = *reinterpret_cast<const float4*>(gx2 + ((T) + 1) * GATES + u * 4); \
        bf16x8 af0 = *reinterpret_cast<const bf16x8*>(hq + (RB) * BUFSTRIDE + 0 * 32); \
        bf16x8 af1 = *reinterpret_cast<const bf16x8*>(hq + (RB) * BUFSTRIDE + 1 * 32); \
        bf16x8 af2 = *reinterpret_cast<const bf16x8*>(hq + (RB) * BUFSTRIDE + 2 * 32); \
        bf16x8 af3 = *reinterpret_cast<const bf16x8*>(hq + (RB) * BUFSTRIDE + 3 * 32); \
        f32x4 a0 = {gcur.x, 0.f, 0.f, 0.f};                                    \
        f32x4 a1 = {gcur.y, 0.f, 0.f, 0.f};                                    \
        f32x4 a2 = {gcur.z, 0.f, 0.f, 0.f};                                    \
        f32x4 a3 = {gcur.w, 0.f, 0.f, 0.f};                                    \
        a0 = __builtin_amdgcn_mfma_f32_16x16x32_bf16(af0, wb_[0][0], a0, 0, 0, 0); \
        a1 = __builtin_amdgcn_mfma_f32_16x16x32_bf16(af0, wb_[1][0], a1, 0, 0, 0); \
        a2 = __builtin_amdgcn_mfma_f32_16x16x32_bf16(af0, wb_[2][0], a2, 0, 0, 0); \
        a3 = __builtin_amdgcn_mfma_f32_16x16x32_bf16(af0, wb_[3][0], a3, 0, 0, 0); \
        a0 = __builtin_amdgcn_mfma_f32_16x16x32_bf16(af1, wb_[0][1], a0, 0, 0, 0); \
        a1 = __builtin_amdgcn_mfma_f32_16x16x32_bf16(af1, wb_[1][1], a1, 0, 0, 0); \
        a2 = __builtin_amdgcn_mfma_f32_16x16x32_bf16(af1, wb_[2][1], a2, 0, 0, 0); \
        a3 = __builtin_amdgcn_mfma_f32_16x16x32_bf16(af1, wb_[3][1], a3, 0, 0, 0); \
        a0 = __builtin_amdgcn_mfma_f32_16x16x32_bf16(af2, wb_[0][2], a0, 0, 0, 0); \
        a1 = __builtin_amdgcn_mfma_f32_16x16x32_bf16(af2, wb_[1][2], a1, 0, 0, 0); \
        a2 = __builtin_amdgcn_mfma_f32_16x16x32_bf16(af2, wb_[2][2], a2, 0, 0, 0); \
        a3 = __builtin_amdgcn_mfma_f32_16x16x32_bf16(af2, wb_[3][2], a3, 0, 0, 0); \
        a0 = __builtin_amdgcn_mfma_f32_16x16x32_bf16(af3, wb_[0][3], a0, 0, 0, 0); \
        a1 = __builtin_amdgcn_mfma_f32_16x16x32_bf16(af3, wb_[1][3], a1, 0, 0, 0); \
        a2 = __builtin_amdgcn_mfma_f32_16x16x32_bf16(af3, wb_[2][3], a2, 0, 0, 0); \
        a3 = __builtin_amdgcn_mfma_f32_16x16x32_bf16(af3, wb_[3][3], a3, 0, 0, 0); \
        float p0 = a0[0] + a0[1];   /* gx + hi-part + lo-part, static regs */  \
        float p1 = a1[0] + a1[1];                                              \
        float p2 = a2[0] + a2[1];                                              \
        float p3 = a3[0] + a3[1];                                              \
        float iv = sigm(p0);                                                   \
        float fv = sigm(p1);                                                   \
        float gv = tanh_fast(p2);                                              \
        float ov = sigm(p3);                                                   \
        c = fv * c + iv * gv;                                                  \
        float h = ov * tanh_fast(c);                                           \
        if (writer) {                                                          \
            unsigned short hi = f2bf(h);                                       \
            wpt[(WB) * BUFSTRIDE] = hi;                                        \
            wpt[(WB) * BUFSTRIDE + PARSTRIDE] = f2bf(h - bf2f(hi));            \
            hs[(T) * HID + u] = h;                                             \
        }                                                                      \
        __syncthreads();                                                       \
    }

    for (int t = 0; t < T_STEPS; t += 2) {
        LSTM_STEP(t, 1, 0);       // even step: read buf1 (zeroed at t=0), write buf0
        LSTM_STEP(t + 1, 0, 1);   // odd step: read buf0, write buf1
    }
#undef LSTM_STEP
}

// ---------------------------------------------------------------------------
// Fallback scan (fused input projection, f32 VALU) — only if d_ws too small.
// ---------------------------------------------------------------------------
__global__ __launch_bounds__(GATES) void k_scan_valu(const float* __restrict__ w_hh,
                                                     float* __restrict__ hs,
                                                     const float* __restrict__ x255,
                                                     const float* __restrict__ w_ih,
                                                     const float* __restrict__ b_ih,
                                                     const float* __restrict__ b_hh) {
    const int g    = threadIdx.x;
    const int quad = g >> 7;

    __shared__ float h_sh[HID];
    __shared__ float act_sh[GATES];
    __shared__ float xs[IN_DIM];

    float4 wv[HID / 4];
    const float4* __restrict__ wrow = reinterpret_cast<const float4*>(w_hh + g * HID);
#pragma unroll
    for (int k = 0; k < HID / 4; ++k) wv[k] = wrow[k];

    float bsum = b_ih[g] + b_hh[g];
    float wih[IN_DIM];
#pragma unroll
    for (int k = 0; k < IN_DIM; ++k) wih[k] = w_ih[g * IN_DIM + k];

    if (g < HID) h_sh[g] = 0.0f;
    float c = 0.0f;
    __syncthreads();

    for (int t = 0; t < T_STEPS; ++t) {
        __syncthreads();
        if (g < IN_DIM) xs[g] = x255[t * IN_DIM + g];
        __syncthreads();
        float a0 = bsum, a1 = 0.0f, a2 = 0.0f, a3 = 0.0f;
#pragma unroll
        for (int k = 0; k < IN_DIM; ++k) a0 += wih[k] * xs[k];

        const float4* __restrict__ h4 = reinterpret_cast<const float4*>(h_sh);
#pragma unroll
        for (int k = 0; k < HID / 4; ++k) {
            float4 hv = h4[k];
            a0 += wv[k].x * hv.x;
            a1 += wv[k].y * hv.y;
            a2 += wv[k].z * hv.z;
            a3 += wv[k].w * hv.w;
        }
        float pre = (a0 + a1) + (a2 + a3);
        float a = (quad == 2) ? tanh_fast(pre) : sigm(pre);
        act_sh[g] = a;
        __syncthreads();

        if (g < HID) {
            float iv = act_sh[g];
            float fv = act_sh[HID + g];
            float gv = act_sh[2 * HID + g];
            float ov = act_sh[3 * HID + g];
            c = fv * c + iv * gv;
            float h = ov * tanh_fast(c);
            h_sh[g] = h;
            hs[t * HID + g] = h;
        }
        __syncthreads();
    }
}

// ---------------------------------------------------------------------------
// Kernel 3: final FC — out[t, o] = dot(hs[t, :], w_fc[o, :]) + b_fc[o]
// ---------------------------------------------------------------------------
__global__ __launch_bounds__(256) void k_fc(const float* __restrict__ hs,
                                            const float* __restrict__ w_fc,
                                            const float* __restrict__ b_fc,
                                            float* __restrict__ out) {
    const int idx = blockIdx.x * blockDim.x + threadIdx.x;
    if (idx >= T_STEPS * OUT_DIM) return;
    const int t = idx / OUT_DIM;
    const int o = idx - t * OUT_DIM;
    const float* __restrict__ hrow = hs + t * HID;
    const float* __restrict__ wrow = w_fc + o * HID;
    float acc = b_fc[o];
#pragma unroll 8
    for (int k = 0; k < HID; ++k) acc += hrow[k] * wrow[k];
    out[idx] = acc;
}

// ---------------------------------------------------------------------------
extern "C" void kernel_launch(void* const* d_in, const int* in_sizes, int n_in,
                              void* d_out, int out_size, void* d_ws, size_t ws_size,
                              hipStream_t stream) {
    const float* x    = (const float*)d_in[0];  // [B, T, I]
    const float* w_ih = (const float*)d_in[1];  // [4H, I]
    const float* w_hh = (const float*)d_in[2];  // [4H, H]
    const float* b_ih = (const float*)d_in[3];  // [4H]
    const float* b_hh = (const float*)d_in[4];  // [4H]
    const float* w_fc = (const float*)d_in[5];  // [OUT, H]
    const float* b_fc = (const float*)d_in[6];  // [OUT]
    float* out = (float*)d_out;                 // [T, OUT]

    // Only batch element B-1 is observable in the reference output.
    const float* x255 = x + (size_t)(BATCH - 1) * T_STEPS * IN_DIM;

    float* hs = (float*)d_ws;                                  // 4096*128 f32 = 2 MB
    float* gx2 = hs + (size_t)T_STEPS * HID;                   // 4096*512 f32 = 8 MB (unit-major)
    const size_t need_full = (size_t)(T_STEPS * HID + T_STEPS * GATES) * sizeof(float);

    if (ws_size >= need_full) {
        k_inproj<<<T_STEPS, GATES, 0, stream>>>(x255, w_ih, b_ih, b_hh, gx2);
        k_scan_mfma<<<1, GATES, 0, stream>>>(gx2, w_hh, hs);
    } else {
        k_scan_valu<<<1, GATES, 0, stream>>>(w_hh, hs, x255, w_ih, b_ih, b_hh);
    }

    const int n = T_STEPS * OUT_DIM;
    k_fc<<<(n + 255) / 256, 256, 0, stream>>>(hs, w_fc, b_fc, out);
}

// Round 8
// 2348.499 us; speedup vs baseline: 1.2434x; 1.0180x over previous
//
#include <hip/hip_runtime.h>
#include <hip/hip_bf16.h>
#include <math.h>

// Problem constants
#define BATCH   256
#define T_STEPS 4096
#define IN_DIM  28
#define HID     128
#define GATES   512   // 4*HID
#define OUT_DIM 10

#define HPAD    16                    // ushort pad: buf/par regions hit different banks
#define PARSTRIDE (HID + HPAD)        // ushorts between par=0 and par=1 regions
#define BUFSTRIDE (2 * PARSTRIDE)     // ushorts between buf 0 and buf 1

typedef short bf16x8 __attribute__((ext_vector_type(8)));  // 8 bf16 in 4 VGPRs
typedef float f32x4  __attribute__((ext_vector_type(4)));

__device__ __forceinline__ float frcp_fast(float x) {
    return __builtin_amdgcn_rcpf(x);
}

__device__ __forceinline__ float sigm(float x) {
    // 1/(1+2^(-x*log2e)) — mul(+exp2) / add / rcp
    float e = __builtin_exp2f(x * -1.44269504f);
    return frcp_fast(1.0f + e);
}

__device__ __forceinline__ float tanh_fast(float x) {
    // tanh(x) = 1 - 2/(1+e^{2x}) — exact at both infinities, no abs/copysign.
    // x>>0: e->inf, rcp->0, r->1.  x<<0: e->0, r->-1.
    float e = __builtin_exp2f(x * 2.88539008f);
    return 1.0f - 2.0f * frcp_fast(1.0f + e);
}

__device__ __forceinline__ unsigned short f2bf(float f) {
    __hip_bfloat16 h = __float2bfloat16(f);   // RNE
    return __builtin_bit_cast(unsigned short, h);
}
__device__ __forceinline__ float bf2f(unsigned short u) {
    return __bfloat162float(__builtin_bit_cast(__hip_bfloat16, u));
}

// ---------------------------------------------------------------------------
// Kernel 1: input projection for batch element 255, UNIT-MAJOR output:
// gx2[t, u, gt] = dot(x255[t,:], w_ih[gt*128+u,:]) + b_ih[..] + b_hh[..]
// ---------------------------------------------------------------------------
__global__ __launch_bounds__(GATES) void k_inproj(const float* __restrict__ x255,
                                                  const float* __restrict__ w_ih,
                                                  const float* __restrict__ b_ih,
                                                  const float* __restrict__ b_hh,
                                                  float* __restrict__ gx2) {
    const int t = blockIdx.x;
    const int g = threadIdx.x;          // gate row 0..511 (i|f|g|o blocks of 128)
    const int unit = g & (HID - 1);
    const int quad = g >> 7;
    __shared__ float xs[IN_DIM];
    if (g < IN_DIM) xs[g] = x255[t * IN_DIM + g];
    __syncthreads();
    float acc = b_ih[g] + b_hh[g];
    const float* __restrict__ wr = w_ih + g * IN_DIM;
#pragma unroll
    for (int k = 0; k < IN_DIM; ++k) acc += wr[k] * xs[k];
    gx2[t * GATES + unit * 4 + quad] = acc;
}

// ---------------------------------------------------------------------------
// Kernel 2 (main): MFMA LSTM scan — 512 threads (8 waves), unit-major,
// operand-swapped (R7-verified): A = h (EVEN rows h_hi, ODD rows h_lo),
// B = W_hh (col n = unit). Lane l: col cidx = its unit; reg0 = hi+gx,
// reg1 = lo -> pre = a[0]+a[1], static regs, no cross-lane epilogue.
// hi/lo precision is FREE here (separate rows of the SAME 16 MFMAs);
// 16 MFMA/wave/step = 4 gates x 4 ktiles is the structural floor.
//
// R8 changes (overlap + chain-shortening, arithmetic unchanged):
//  - software-pipelined gate order: i/f MFMAs -> g/o MFMAs interleaved with
//    sigm(i),sigm(f),f*c (in-order issue => sigm work co-issues under the
//    co-resident wave's MFMAs; MFMA pipe stays fed during VALU chain)
//  - tanh = 1-2/(1+e^{2x}): no abs/copysign on the critical chain
//  - writer tail distributed: q0 -> h_hi, q1 -> h_lo, q2 -> hs (all
//    q-replicas compute identical h; shorter pre-barrier tail)
// ---------------------------------------------------------------------------
__global__ __attribute__((amdgpu_flat_work_group_size(512, 512),
                          amdgpu_waves_per_eu(2, 2)))
void k_scan_mfma(const float* __restrict__ gx2,
                 const float* __restrict__ w_hh,
                 float* __restrict__ hs) {
    const int tid   = threadIdx.x;
    const int w     = tid >> 6;         // wave 0..7
    const int l     = tid & 63;         // lane 0..63
    const int q     = l >> 4;           // k-group / D row-group 0..3
    const int cidx  = l & 15;           // D column = unit within wave
    const int par   = cidx & 1;         // A-row parity: 0 -> h_hi, 1 -> h_lo
    const int ubase = w * 16;
    const int u     = ubase + cidx;     // unit this lane finalizes

    __shared__ __align__(16) unsigned short hb[2 * BUFSTRIDE];

    // ---- one-time: B-frags wb_[gate_type][kt] (64 VGPRs) ----
    // lane l holds B[k = kt*32 + q*8 + j][col = cidx] = W_hh[gt*128+u][k]
    bf16x8 wb_[4][4];
#pragma unroll
    for (int gt = 0; gt < 4; ++gt) {
        const int row = gt * HID + u;
        const float* __restrict__ wr = w_hh + row * HID;
#pragma unroll
        for (int kt = 0; kt < 4; ++kt) {
            const int k0 = kt * 32 + q * 8;
            bf16x8 v;
#pragma unroll
            for (int j = 0; j < 8; ++j) v[j] = (short)f2bf(wr[k0 + j]);
            wb_[gt][kt] = v;
        }
    }

    // zero both buffers (both parities)
    if (tid < HID) {
        hb[0 * BUFSTRIDE + 0 * PARSTRIDE + tid] = 0;
        hb[0 * BUFSTRIDE + 1 * PARSTRIDE + tid] = 0;
        hb[1 * BUFSTRIDE + 0 * PARSTRIDE + tid] = 0;
        hb[1 * BUFSTRIDE + 1 * PARSTRIDE + tid] = 0;
    }
    float c = 0.0f;                     // cell state (4x replicated per unit)
    // loop-invariant per-lane bases
    const unsigned short* __restrict__ hq = &hb[par * PARSTRIDE + q * 8]; // A-frag read base
    unsigned short* __restrict__ wpt = &hb[u];                            // writer base

    float4 gnext = *reinterpret_cast<const float4*>(gx2 + u * 4);  // t=0
    __syncthreads();

#define LSTM_STEP(T, RB, WB)                                                   \
    {                                                                          \
        float4 gcur = gnext;                                                   \
        if ((T) + 1 < T_STEPS)                                                 \
            gnext = *reinterpret_cast<const float4*>(gx2 + ((T) + 1) * GATES + u * 4); \
        bf16x8 af0 = *reinterpret_cast<const bf16x8*>(hq + (RB) * BUFSTRIDE + 0 * 32); \
        bf16x8 af1 = *reinterpret_cast<const bf16x8*>(hq + (RB) * BUFSTRIDE + 1 * 32); \
        bf16x8 af2 = *reinterpret_cast<const bf16x8*>(hq + (RB) * BUFSTRIDE + 2 * 32); \
        bf16x8 af3 = *reinterpret_cast<const bf16x8*>(hq + (RB) * BUFSTRIDE + 3 * 32); \
        f32x4 a0 = {gcur.x, 0.f, 0.f, 0.f};                                    \
        f32x4 a1 = {gcur.y, 0.f, 0.f, 0.f};                                    \
        /* gates i,f first */                                                  \
        a0 = __builtin_amdgcn_mfma_f32_16x16x32_bf16(af0, wb_[0][0], a0, 0, 0, 0); \
        a1 = __builtin_amdgcn_mfma_f32_16x16x32_bf16(af0, wb_[1][0], a1, 0, 0, 0); \
        a0 = __builtin_amdgcn_mfma_f32_16x16x32_bf16(af1, wb_[0][1], a0, 0, 0, 0); \
        a1 = __builtin_amdgcn_mfma_f32_16x16x32_bf16(af1, wb_[1][1], a1, 0, 0, 0); \
        a0 = __builtin_amdgcn_mfma_f32_16x16x32_bf16(af2, wb_[0][2], a0, 0, 0, 0); \
        a1 = __builtin_amdgcn_mfma_f32_16x16x32_bf16(af2, wb_[1][2], a1, 0, 0, 0); \
        a0 = __builtin_amdgcn_mfma_f32_16x16x32_bf16(af3, wb_[0][3], a0, 0, 0, 0); \
        a1 = __builtin_amdgcn_mfma_f32_16x16x32_bf16(af3, wb_[1][3], a1, 0, 0, 0); \
        f32x4 a2 = {gcur.z, 0.f, 0.f, 0.f};                                    \
        f32x4 a3 = {gcur.w, 0.f, 0.f, 0.f};                                    \
        /* start g,o MFMAs; i/f epilogue issues between them (in-order issue  \
           => our VALU co-schedules under the other wave's MFMAs) */           \
        a2 = __builtin_amdgcn_mfma_f32_16x16x32_bf16(af0, wb_[2][0], a2, 0, 0, 0); \
        a3 = __builtin_amdgcn_mfma_f32_16x16x32_bf16(af0, wb_[3][0], a3, 0, 0, 0); \
        float p0 = a0[0] + a0[1];                                              \
        float p1 = a1[0] + a1[1];                                              \
        float iv = sigm(p0);                                                   \
        a2 = __builtin_amdgcn_mfma_f32_16x16x32_bf16(af1, wb_[2][1], a2, 0, 0, 0); \
        a3 = __builtin_amdgcn_mfma_f32_16x16x32_bf16(af1, wb_[3][1], a3, 0, 0, 0); \
        float fv = sigm(p1);                                                   \
        float fc_ = fv * c;                                                    \
        a2 = __builtin_amdgcn_mfma_f32_16x16x32_bf16(af2, wb_[2][2], a2, 0, 0, 0); \
        a3 = __builtin_amdgcn_mfma_f32_16x16x32_bf16(af2, wb_[3][2], a3, 0, 0, 0); \
        a2 = __builtin_amdgcn_mfma_f32_16x16x32_bf16(af3, wb_[2][3], a2, 0, 0, 0); \
        a3 = __builtin_amdgcn_mfma_f32_16x16x32_bf16(af3, wb_[3][3], a3, 0, 0, 0); \
        float p2 = a2[0] + a2[1];                                              \
        float p3 = a3[0] + a3[1];                                              \
        float gv = tanh_fast(p2);                                              \
        float ov = sigm(p3);                                                   \
        c = fc_ + iv * gv;                                                     \
        float h = ov * tanh_fast(c);                                           \
        /* distributed writer tail: all q-replicas hold identical h */         \
        unsigned short hi = f2bf(h);                                           \
        if (q == 0) wpt[(WB) * BUFSTRIDE] = hi;                                \
        if (q == 1) wpt[(WB) * BUFSTRIDE + PARSTRIDE] = f2bf(h - bf2f(hi));    \
        if (q == 2) hs[(T) * HID + u] = h;                                     \
        __syncthreads();                                                       \
    }

    for (int t = 0; t < T_STEPS; t += 2) {
        LSTM_STEP(t, 1, 0);       // even step: read buf1 (zeroed at t=0), write buf0
        LSTM_STEP(t + 1, 0, 1);   // odd step: read buf0, write buf1
    }
#undef LSTM_STEP
}

// ---------------------------------------------------------------------------
// Fallback scan (fused input projection, f32 VALU) — only if d_ws too small.
// ---------------------------------------------------------------------------
__global__ __launch_bounds__(GATES) void k_scan_valu(const float* __restrict__ w_hh,
                                                     float* __restrict__ hs,
                                                     const float* __restrict__ x255,
                                                     const float* __restrict__ w_ih,
                                                     const float* __restrict__ b_ih,
                                                     const float* __restrict__ b_hh) {
    const int g    = threadIdx.x;
    const int quad = g >> 7;

    __shared__ float h_sh[HID];
    __shared__ float act_sh[GATES];
    __shared__ float xs[IN_DIM];

    float4 wv[HID / 4];
    const float4* __restrict__ wrow = reinterpret_cast<const float4*>(w_hh + g * HID);
#pragma unroll
    for (int k = 0; k < HID / 4; ++k) wv[k] = wrow[k];

    float bsum = b_ih[g] + b_hh[g];
    float wih[IN_DIM];
#pragma unroll
    for (int k = 0; k < IN_DIM; ++k) wih[k] = w_ih[g * IN_DIM + k];

    if (g < HID) h_sh[g] = 0.0f;
    float c = 0.0f;
    __syncthreads();

    for (int t = 0; t < T_STEPS; ++t) {
        __syncthreads();
        if (g < IN_DIM) xs[g] = x255[t * IN_DIM + g];
        __syncthreads();
        float a0 = bsum, a1 = 0.0f, a2 = 0.0f, a3 = 0.0f;
#pragma unroll
        for (int k = 0; k < IN_DIM; ++k) a0 += wih[k] * xs[k];

        const float4* __restrict__ h4 = reinterpret_cast<const float4*>(h_sh);
#pragma unroll
        for (int k = 0; k < HID / 4; ++k) {
            float4 hv = h4[k];
            a0 += wv[k].x * hv.x;
            a1 += wv[k].y * hv.y;
            a2 += wv[k].z * hv.z;
            a3 += wv[k].w * hv.w;
        }
        float pre = (a0 + a1) + (a2 + a3);
        float a = (quad == 2) ? tanh_fast(pre) : sigm(pre);
        act_sh[g] = a;
        __syncthreads();

        if (g < HID) {
            float iv = act_sh[g];
            float fv = act_sh[HID + g];
            float gv = act_sh[2 * HID + g];
            float ov = act_sh[3 * HID + g];
            c = fv * c + iv * gv;
            float h = ov * tanh_fast(c);
            h_sh[g] = h;
            hs[t * HID + g] = h;
        }
        __syncthreads();
    }
}

// ---------------------------------------------------------------------------
// Kernel 3: final FC — out[t, o] = dot(hs[t, :], w_fc[o, :]) + b_fc[o]
// ---------------------------------------------------------------------------
__global__ __launch_bounds__(256) void k_fc(const float* __restrict__ hs,
                                            const float* __restrict__ w_fc,
                                            const float* __restrict__ b_fc,
                                            float* __restrict__ out) {
    const int idx = blockIdx.x * blockDim.x + threadIdx.x;
    if (idx >= T_STEPS * OUT_DIM) return;
    const int t = idx / OUT_DIM;
    const int o = idx - t * OUT_DIM;
    const float* __restrict__ hrow = hs + t * HID;
    const float* __restrict__ wrow = w_fc + o * HID;
    float acc = b_fc[o];
#pragma unroll 8
    for (int k = 0; k < HID; ++k) acc += hrow[k] * wrow[k];
    out[idx] = acc;
}

// ---------------------------------------------------------------------------
extern "C" void kernel_launch(void* const* d_in, const int* in_sizes, int n_in,
                              void* d_out, int out_size, void* d_ws, size_t ws_size,
                              hipStream_t stream) {
    const float* x    = (const float*)d_in[0];  // [B, T, I]
    const float* w_ih = (const float*)d_in[1];  // [4H, I]
    const float* w_hh = (const float*)d_in[2];  // [4H, H]
    const float* b_ih = (const float*)d_in[3];  // [4H]
    const float* b_hh = (const float*)d_in[4];  // [4H]
    const float* w_fc = (const float*)d_in[5];  // [OUT, H]
    const float* b_fc = (const float*)d_in[6];  // [OUT]
    float* out = (float*)d_out;                 // [T, OUT]

    // Only batch element B-1 is observable in the reference output.
    const float* x255 = x + (size_t)(BATCH - 1) * T_STEPS * IN_DIM;

    float* hs = (float*)d_ws;                                  // 4096*128 f32 = 2 MB
    float* gx2 = hs + (size_t)T_STEPS * HID;                   // 4096*512 f32 = 8 MB (unit-major)
    const size_t need_full = (size_t)(T_STEPS * HID + T_STEPS * GATES) * sizeof(float);

    if (ws_size >= need_full) {
        k_inproj<<<T_STEPS, GATES, 0, stream>>>(x255, w_ih, b_ih, b_hh, gx2);
        k_scan_mfma<<<1, GATES, 0, stream>>>(gx2, w_hh, hs);
    } else {
        k_scan_valu<<<1, GATES, 0, stream>>>(w_hh, hs, x255, w_ih, b_ih, b_hh);
    }

    const int n = T_STEPS * OUT_DIM;
    k_fc<<<(n + 255) / 256, 256, 0, stream>>>(hs, w_fc, b_fc, out);
}

// Round 9
// 2308.475 us; speedup vs baseline: 1.2650x; 1.0173x over previous
//
#include <hip/hip_runtime.h>
#include <hip/hip_bf16.h>
#include <math.h>

// Problem constants
#define BATCH   256
#define T_STEPS 4096
#define IN_DIM  28
#define HID     128
#define GATES   512   // 4*HID
#define OUT_DIM 10

#define HPAD    16                    // ushort pad: buf/par regions hit different banks
#define PARSTRIDE (HID + HPAD)        // ushorts between par=0 and par=1 regions
#define BUFSTRIDE (2 * PARSTRIDE)     // ushorts between buf 0 and buf 1

typedef short bf16x8 __attribute__((ext_vector_type(8)));  // 8 bf16 in 4 VGPRs
typedef float f32x4  __attribute__((ext_vector_type(4)));

#define SGB __builtin_amdgcn_sched_group_barrier
// LLVM SchedGroupMask: VALU=0x2, MFMA=0x8, DS_READ=0x100

__device__ __forceinline__ float frcp_fast(float x) {
    return __builtin_amdgcn_rcpf(x);
}

__device__ __forceinline__ unsigned short f2bf(float f) {
    __hip_bfloat16 h = __float2bfloat16(f);   // RNE
    return __builtin_bit_cast(unsigned short, h);
}
__device__ __forceinline__ float bf2f(unsigned short u) {
    return __bfloat162float(__builtin_bit_cast(__hip_bfloat16, u));
}

__device__ __forceinline__ float sigm(float x) {
    float e = __builtin_exp2f(x * -1.44269504f);
    return frcp_fast(1.0f + e);
}
__device__ __forceinline__ float tanh_fast(float x) {
    // tanh(x) = 1 - 2/(1+e^{2x}) — exact at both infinities
    float e = __builtin_exp2f(x * 2.88539008f);
    return 1.0f - 2.0f * frcp_fast(1.0f + e);
}

// ---------------------------------------------------------------------------
// Kernel 1: input projection for batch element 255, UNIT-MAJOR output:
// gx2[t, u, gt] = dot(x255[t,:], w_ih[gt*128+u,:]) + b_ih[..] + b_hh[..]
// ---------------------------------------------------------------------------
__global__ __launch_bounds__(GATES) void k_inproj(const float* __restrict__ x255,
                                                  const float* __restrict__ w_ih,
                                                  const float* __restrict__ b_ih,
                                                  const float* __restrict__ b_hh,
                                                  float* __restrict__ gx2) {
    const int t = blockIdx.x;
    const int g = threadIdx.x;          // gate row 0..511 (i|f|g|o blocks of 128)
    const int unit = g & (HID - 1);
    const int quad = g >> 7;
    __shared__ float xs[IN_DIM];
    if (g < IN_DIM) xs[g] = x255[t * IN_DIM + g];
    __syncthreads();
    float acc = b_ih[g] + b_hh[g];
    const float* __restrict__ wr = w_ih + g * IN_DIM;
#pragma unroll
    for (int k = 0; k < IN_DIM; ++k) acc += wr[k] * xs[k];
    gx2[t * GATES + unit * 4 + quad] = acc;
}

// ---------------------------------------------------------------------------
// Kernel 2 (main): MFMA LSTM scan — 512 threads (8 waves), unit-major,
// operand-swapped (R7-verified): A = h (EVEN rows h_hi, ODD rows h_lo),
// B = W_hh (col n = unit). Lane: col cidx = its unit; reg0 = hi-part,
// reg1 = lo-part -> pre = a[0]+a[1]+gx, static regs.
//
// R9 (R8 counters: step = 509cy MFMA + 783cy VALU/trans, nearly serial):
//  - FULL interleave: gate order g,o,i,f; each activation chain threaded
//    one-op-at-a-time BETWEEN the remaining MFMAs (in-order issue => VALU
//    fills this wave's MFMA pipe-stall slots). Tail = f-sigm, c, tanh(c),
//    h, cvt, write only.
//  - zero-cost acc init: persistent zero-quad as C of each chain's first
//    MFMA (D != C is legal) — kills 16 movs/step; gx added in the p-adds,
//    removing the gnext load from MFMA deps.
//  - sched_group_barrier pins (DS_READ 4 -> MFMA 4 -> 12x{MFMA 1, VALU 2})
//    to keep the scheduler from re-bunching MFMAs above the VALU.
// ---------------------------------------------------------------------------
__global__ __attribute__((amdgpu_flat_work_group_size(512, 512),
                          amdgpu_waves_per_eu(2, 2)))
void k_scan_mfma(const float* __restrict__ gx2,
                 const float* __restrict__ w_hh,
                 float* __restrict__ hs) {
    const int tid   = threadIdx.x;
    const int w     = tid >> 6;         // wave 0..7
    const int l     = tid & 63;         // lane 0..63
    const int q     = l >> 4;           // k-group / D row-group 0..3
    const int cidx  = l & 15;           // D column = unit within wave
    const int par   = cidx & 1;         // A-row parity: 0 -> h_hi, 1 -> h_lo
    const int ubase = w * 16;
    const int u     = ubase + cidx;     // unit this lane finalizes

    __shared__ __align__(16) unsigned short hb[2 * BUFSTRIDE];

    // ---- one-time: B-frags wb_[gate_type][kt] (64 VGPRs) ----
    // lane l holds B[k = kt*32 + q*8 + j][col = cidx] = W_hh[gt*128+u][k]
    bf16x8 wb_[4][4];
#pragma unroll
    for (int gt = 0; gt < 4; ++gt) {
        const int row = gt * HID + u;
        const float* __restrict__ wr = w_hh + row * HID;
#pragma unroll
        for (int kt = 0; kt < 4; ++kt) {
            const int k0 = kt * 32 + q * 8;
            bf16x8 v;
#pragma unroll
            for (int j = 0; j < 8; ++j) v[j] = (short)f2bf(wr[k0 + j]);
            wb_[gt][kt] = v;
        }
    }

    // zero both buffers (both parities)
    if (tid < HID) {
        hb[0 * BUFSTRIDE + 0 * PARSTRIDE + tid] = 0;
        hb[0 * BUFSTRIDE + 1 * PARSTRIDE + tid] = 0;
        hb[1 * BUFSTRIDE + 0 * PARSTRIDE + tid] = 0;
        hb[1 * BUFSTRIDE + 1 * PARSTRIDE + tid] = 0;
    }
    float c = 0.0f;                     // cell state (4x replicated per unit)
    const unsigned short* __restrict__ hq = &hb[par * PARSTRIDE + q * 8]; // A-frag base
    unsigned short* __restrict__ wpt = &hb[u];                            // writer base
    const f32x4 ZQ = {0.f, 0.f, 0.f, 0.f};   // persistent zero C-operand

    float4 gnext = *reinterpret_cast<const float4*>(gx2 + u * 4);  // t=0
    __syncthreads();

#define MF(A, G, K, C_) __builtin_amdgcn_mfma_f32_16x16x32_bf16((A), wb_[G][K], (C_), 0, 0, 0)

#define LSTM_STEP(T, RB, WB)                                                   \
    {                                                                          \
        float4 gcur = gnext;                                                   \
        if ((T) + 1 < T_STEPS)                                                 \
            gnext = *reinterpret_cast<const float4*>(gx2 + ((T) + 1) * GATES + u * 4); \
        bf16x8 af0 = *reinterpret_cast<const bf16x8*>(hq + (RB) * BUFSTRIDE + 0 * 32); \
        bf16x8 af1 = *reinterpret_cast<const bf16x8*>(hq + (RB) * BUFSTRIDE + 1 * 32); \
        bf16x8 af2 = *reinterpret_cast<const bf16x8*>(hq + (RB) * BUFSTRIDE + 2 * 32); \
        bf16x8 af3 = *reinterpret_cast<const bf16x8*>(hq + (RB) * BUFSTRIDE + 3 * 32); \
        /* g-gate chain first (its tanh is the longest activation) */          \
        f32x4 a2 = MF(af0, 2, 0, ZQ);                                          \
        a2 = MF(af1, 2, 1, a2);                                                \
        a2 = MF(af2, 2, 2, a2);                                                \
        a2 = MF(af3, 2, 3, a2);                                                \
        /* o-chain, g-activation threaded between */                           \
        f32x4 a3 = MF(af0, 3, 0, ZQ);                                          \
        float p2 = (a2[0] + a2[1]) + gcur.z;                                   \
        a3 = MF(af1, 3, 1, a3);                                                \
        float eg = __builtin_exp2f(p2 * 2.88539008f);                          \
        a3 = MF(af2, 3, 2, a3);                                                \
        float dg = 1.0f + eg;                                                  \
        a3 = MF(af3, 3, 3, a3);                                                \
        float gv = __builtin_fmaf(-2.0f, frcp_fast(dg), 1.0f);                 \
        /* i-chain, o-activation threaded between */                           \
        f32x4 a0 = MF(af0, 0, 0, ZQ);                                          \
        float p3 = (a3[0] + a3[1]) + gcur.w;                                   \
        a0 = MF(af1, 0, 1, a0);                                                \
        float eo = __builtin_exp2f(p3 * -1.44269504f);                         \
        a0 = MF(af2, 0, 2, a0);                                                \
        float dosum = 1.0f + eo;                                               \
        a0 = MF(af3, 0, 3, a0);                                                \
        float ov = frcp_fast(dosum);                                           \
        /* f-chain, i-activation threaded between */                           \
        f32x4 a1 = MF(af0, 1, 0, ZQ);                                          \
        float p0 = (a0[0] + a0[1]) + gcur.x;                                   \
        a1 = MF(af1, 1, 1, a1);                                                \
        float ei = __builtin_exp2f(p0 * -1.44269504f);                         \
        a1 = MF(af2, 1, 2, a1);                                                \
        float di = 1.0f + ei;                                                  \
        a1 = MF(af3, 1, 3, a1);                                                \
        float iv = frcp_fast(di);                                              \
        /* tail */                                                             \
        float p1 = (a1[0] + a1[1]) + gcur.y;                                   \
        float ef = __builtin_exp2f(p1 * -1.44269504f);                         \
        float fv = frcp_fast(1.0f + ef);                                       \
        float ig = iv * gv;                                                    \
        c = __builtin_fmaf(fv, c, ig);                                         \
        float ec = __builtin_exp2f(c * 2.88539008f);                           \
        float th = __builtin_fmaf(-2.0f, frcp_fast(1.0f + ec), 1.0f);          \
        float h = ov * th;                                                     \
        unsigned short hi = f2bf(h);                                           \
        if (q == 0) wpt[(WB) * BUFSTRIDE] = hi;                                \
        if (q == 1) wpt[(WB) * BUFSTRIDE + PARSTRIDE] = f2bf(h - bf2f(hi));    \
        if (q == 2) hs[(T) * HID + u] = h;                                     \
        /* pin the interleave: reads, g-burst, then MFMA/VALU alternation */   \
        SGB(0x100, 4, 0);                                                      \
        SGB(0x008, 4, 0);                                                      \
        SGB(0x008, 1, 0); SGB(0x002, 2, 0);                                    \
        SGB(0x008, 1, 0); SGB(0x002, 2, 0);                                    \
        SGB(0x008, 1, 0); SGB(0x002, 2, 0);                                    \
        SGB(0x008, 1, 0); SGB(0x002, 2, 0);                                    \
        SGB(0x008, 1, 0); SGB(0x002, 2, 0);                                    \
        SGB(0x008, 1, 0); SGB(0x002, 2, 0);                                    \
        SGB(0x008, 1, 0); SGB(0x002, 2, 0);                                    \
        SGB(0x008, 1, 0); SGB(0x002, 2, 0);                                    \
        SGB(0x008, 1, 0); SGB(0x002, 2, 0);                                    \
        SGB(0x008, 1, 0); SGB(0x002, 2, 0);                                    \
        SGB(0x008, 1, 0); SGB(0x002, 2, 0);                                    \
        SGB(0x008, 1, 0); SGB(0x002, 2, 0);                                    \
        __syncthreads();                                                       \
    }

    for (int t = 0; t < T_STEPS; t += 2) {
        LSTM_STEP(t, 1, 0);       // even step: read buf1 (zeroed at t=0), write buf0
        LSTM_STEP(t + 1, 0, 1);   // odd step: read buf0, write buf1
    }
#undef LSTM_STEP
#undef MF
}

// ---------------------------------------------------------------------------
// Fallback scan (fused input projection, f32 VALU) — only if d_ws too small.
// ---------------------------------------------------------------------------
__global__ __launch_bounds__(GATES) void k_scan_valu(const float* __restrict__ w_hh,
                                                     float* __restrict__ hs,
                                                     const float* __restrict__ x255,
                                                     const float* __restrict__ w_ih,
                                                     const float* __restrict__ b_ih,
                                                     const float* __restrict__ b_hh) {
    const int g    = threadIdx.x;
    const int quad = g >> 7;

    __shared__ float h_sh[HID];
    __shared__ float act_sh[GATES];
    __shared__ float xs[IN_DIM];

    float4 wv[HID / 4];
    const float4* __restrict__ wrow = reinterpret_cast<const float4*>(w_hh + g * HID);
#pragma unroll
    for (int k = 0; k < HID / 4; ++k) wv[k] = wrow[k];

    float bsum = b_ih[g] + b_hh[g];
    float wih[IN_DIM];
#pragma unroll
    for (int k = 0; k < IN_DIM; ++k) wih[k] = w_ih[g * IN_DIM + k];

    if (g < HID) h_sh[g] = 0.0f;
    float c = 0.0f;
    __syncthreads();

    for (int t = 0; t < T_STEPS; ++t) {
        __syncthreads();
        if (g < IN_DIM) xs[g] = x255[t * IN_DIM + g];
        __syncthreads();
        float a0 = bsum, a1 = 0.0f, a2 = 0.0f, a3 = 0.0f;
#pragma unroll
        for (int k = 0; k < IN_DIM; ++k) a0 += wih[k] * xs[k];

        const float4* __restrict__ h4 = reinterpret_cast<const float4*>(h_sh);
#pragma unroll
        for (int k = 0; k < HID / 4; ++k) {
            float4 hv = h4[k];
            a0 += wv[k].x * hv.x;
            a1 += wv[k].y * hv.y;
            a2 += wv[k].z * hv.z;
            a3 += wv[k].w * hv.w;
        }
        float pre = (a0 + a1) + (a2 + a3);
        float a = (quad == 2) ? tanh_fast(pre) : sigm(pre);
        act_sh[g] = a;
        __syncthreads();

        if (g < HID) {
            float iv = act_sh[g];
            float fv = act_sh[HID + g];
            float gv = act_sh[2 * HID + g];
            float ov = act_sh[3 * HID + g];
            c = fv * c + iv * gv;
            float h = ov * tanh_fast(c);
            h_sh[g] = h;
            hs[t * HID + g] = h;
        }
        __syncthreads();
    }
}

// ---------------------------------------------------------------------------
// Kernel 3: final FC — out[t, o] = dot(hs[t, :], w_fc[o, :]) + b_fc[o]
// ---------------------------------------------------------------------------
__global__ __launch_bounds__(256) void k_fc(const float* __restrict__ hs,
                                            const float* __restrict__ w_fc,
                                            const float* __restrict__ b_fc,
                                            float* __restrict__ out) {
    const int idx = blockIdx.x * blockDim.x + threadIdx.x;
    if (idx >= T_STEPS * OUT_DIM) return;
    const int t = idx / OUT_DIM;
    const int o = idx - t * OUT_DIM;
    const float* __restrict__ hrow = hs + t * HID;
    const float* __restrict__ wrow = w_fc + o * HID;
    float acc = b_fc[o];
#pragma unroll 8
    for (int k = 0; k < HID; ++k) acc += hrow[k] * wrow[k];
    out[idx] = acc;
}

// ---------------------------------------------------------------------------
extern "C" void kernel_launch(void* const* d_in, const int* in_sizes, int n_in,
                              void* d_out, int out_size, void* d_ws, size_t ws_size,
                              hipStream_t stream) {
    const float* x    = (const float*)d_in[0];  // [B, T, I]
    const float* w_ih = (const float*)d_in[1];  // [4H, I]
    const float* w_hh = (const float*)d_in[2];  // [4H, H]
    const float* b_ih = (const float*)d_in[3];  // [4H]
    const float* b_hh = (const float*)d_in[4];  // [4H]
    const float* w_fc = (const float*)d_in[5];  // [OUT, H]
    const float* b_fc = (const float*)d_in[6];  // [OUT]
    float* out = (float*)d_out;                 // [T, OUT]

    // Only batch element B-1 is observable in the reference output.
    const float* x255 = x + (size_t)(BATCH - 1) * T_STEPS * IN_DIM;

    float* hs = (float*)d_ws;                                  // 4096*128 f32 = 2 MB
    float* gx2 = hs + (size_t)T_STEPS * HID;                   // 4096*512 f32 = 8 MB (unit-major)
    const size_t need_full = (size_t)(T_STEPS * HID + T_STEPS * GATES) * sizeof(float);

    if (ws_size >= need_full) {
        k_inproj<<<T_STEPS, GATES, 0, stream>>>(x255, w_ih, b_ih, b_hh, gx2);
        k_scan_mfma<<<1, GATES, 0, stream>>>(gx2, w_hh, hs);
    } else {
        k_scan_valu<<<1, GATES, 0, stream>>>(w_hh, hs, x255, w_ih, b_ih, b_hh);
    }

    const int n = T_STEPS * OUT_DIM;
    k_fc<<<(n + 255) / 256, 256, 0, stream>>>(hs, w_fc, b_fc, out);
}